// Round 5
// baseline (28.969 us; speedup 1.0000x reference)
//
#include <hip/hip_runtime.h>

// FeatureViewEncoder: per-feature Conv1d(1,H,3) + mask + max-over-time.
// out[b,f,h] = max_{l: mask[b,l]!=0} ( sum_k x[b,l+k,f]*w[f,h,k] + bias[f,h] ), else -1e9.
// PROBE ROUND: identical kernel to R4, launched TWICE back-to-back on the same
// stream. Output is recomputed identically (deterministic). The measured
// dur_us delta vs single-launch (17.18 us) isolates true kernel device time
// from fixed graph-replay overhead.

#define NEG_INF_F (-1e9f)

typedef float v2f __attribute__((ext_vector_type(2)));

constexpr int B_ = 128;
constexpr int V_ = 200;
constexpr int F_ = 64;
constexpr int H_ = 128;
constexpr int L_ = V_ - 3 + 1;   // 198

constexpr int NTHR = 256;
constexpr int HPT  = 8;            // h-outputs per thread (4 packed pairs)
constexpr int TPF  = H_ / HPT;     // 16 threads per feature
constexpr int FG   = NTHR / TPF;   // 16 features per block
constexpr int XSTR = 204;          // LDS row stride (mult of 4; spreads row-start banks)

__global__ __launch_bounds__(NTHR)
void fve_kernel(const float* __restrict__ x,     // [B,V,F]
                const int*   __restrict__ mask,  // [B,1,L]
                const float* __restrict__ w,     // [F,H,K]
                const float* __restrict__ bias,  // [F,H]
                float* __restrict__ out)         // [B,F,H]
{
    __shared__ __align__(16) float xs[FG][XSTR];
    __shared__ __align__(16) int   vlist[((L_ + 3) / 4) * 4];
    __shared__ int vcnt;

    const int b  = blockIdx.x >> 2;        // grid = B * (F/FG) = 512
    const int f0 = (blockIdx.x & 3) * FG;
    const int t  = threadIdx.x;

    if (t == 0) vcnt = 0;
    __syncthreads();

    // Stage x[b, :, f0:f0+16] -> LDS transposed to xs[f_local][v].
    for (int idx = t; idx < V_ * 4; idx += NTHR) {
        const int v = idx >> 2, q = idx & 3;
        const float4 vec = *reinterpret_cast<const float4*>(
            x + ((size_t)b * V_ + v) * F_ + f0 + q * 4);
        const int fl = q * 4;
        xs[fl + 0][v] = vec.x;
        xs[fl + 1][v] = vec.y;
        xs[fl + 2][v] = vec.z;
        xs[fl + 3][v] = vec.w;
    }

    // Compact valid time-steps (order irrelevant for max).
    for (int l = t; l < L_; l += NTHR) {
        if (mask[b * L_ + l] != 0) {
            const int p = atomicAdd(&vcnt, 1);
            vlist[p] = l;
        }
    }
    __syncthreads();

    const int f_local = t >> 4;            // 0..15
    const int f       = f0 + f_local;
    const int h0      = (t & 15) * HPT;    // 0,8,...,120

    const float* wp = w + ((size_t)f * H_ + h0) * 3;
    float wt[24];
#pragma unroll
    for (int j = 0; j < 6; ++j)
        *reinterpret_cast<float4*>(&wt[j * 4]) =
            *reinterpret_cast<const float4*>(wp + j * 4);

    float bsc[8];
    *reinterpret_cast<float4*>(&bsc[0]) =
        *reinterpret_cast<const float4*>(bias + (size_t)f * H_ + h0);
    *reinterpret_cast<float4*>(&bsc[4]) =
        *reinterpret_cast<const float4*>(bias + (size_t)f * H_ + h0 + 4);

    v2f wp0[4], wp1[4], wp2[4], bpk[4], mpk[4];
#pragma unroll
    for (int p = 0; p < 4; ++p) {
        wp0[p] = (v2f){wt[6 * p + 0], wt[6 * p + 3]};
        wp1[p] = (v2f){wt[6 * p + 1], wt[6 * p + 4]};
        wp2[p] = (v2f){wt[6 * p + 2], wt[6 * p + 5]};
        bpk[p] = (v2f){bsc[2 * p], bsc[2 * p + 1]};
        mpk[p] = (v2f){NEG_INF_F, NEG_INF_F};
    }

    const float* row = &xs[f_local][0];
    const int n  = vcnt;
    const int n4 = n & ~3;
    const int4* vq = reinterpret_cast<const int4*>(vlist);

#define PROC(lv)                                                              \
    do {                                                                      \
        const int   l  = (lv);                                                \
        const float x0 = row[l], x1 = row[l + 1], x2 = row[l + 2];            \
        const v2f X0 = (v2f){x0, x0};                                         \
        const v2f X1 = (v2f){x1, x1};                                         \
        const v2f X2 = (v2f){x2, x2};                                         \
        _Pragma("unroll")                                                     \
        for (int p = 0; p < 4; ++p) {                                         \
            const v2f c = __builtin_elementwise_fma(X0, wp0[p],               \
                          __builtin_elementwise_fma(X1, wp1[p],               \
                          __builtin_elementwise_fma(X2, wp2[p], bpk[p])));    \
            mpk[p] = __builtin_elementwise_max(mpk[p], c);                    \
        }                                                                     \
    } while (0)

    for (int i = 0; i < n4; i += 4) {
        const int4 ls = vq[i >> 2];
        PROC(ls.x);
        PROC(ls.y);
        PROC(ls.z);
        PROC(ls.w);
    }
    for (int i = n4; i < n; ++i) PROC(vlist[i]);
#undef PROC

    float* op = out + ((size_t)b * F_ + f) * H_ + h0;
    *reinterpret_cast<float4*>(op) =
        make_float4(mpk[0].x, mpk[0].y, mpk[1].x, mpk[1].y);
    *reinterpret_cast<float4*>(op + 4) =
        make_float4(mpk[2].x, mpk[2].y, mpk[3].x, mpk[3].y);
}

extern "C" void kernel_launch(void* const* d_in, const int* in_sizes, int n_in,
                              void* d_out, int out_size, void* d_ws, size_t ws_size,
                              hipStream_t stream) {
    const float* x    = (const float*)d_in[0];  // input_visit
    const int*   mask = (const int*)d_in[1];    // visit_mask
    const float* w    = (const float*)d_in[2];  // conv_w
    const float* bias = (const float*)d_in[3];  // conv_b
    float* out = (float*)d_out;

    const int grid = B_ * (F_ / FG);  // 512
    // PROBE: two identical launches. Second recomputes the same output
    // (deterministic); dur_us delta vs R4 == true kernel device time.
    fve_kernel<<<grid, NTHR, 0, stream>>>(x, mask, w, bias, out);
    fve_kernel<<<grid, NTHR, 0, stream>>>(x, mask, w, bias, out);
}

// Round 6
// 16.174 us; speedup vs baseline: 1.7911x; 1.7911x over previous
//
#include <hip/hip_runtime.h>

// FeatureViewEncoder: per-feature Conv1d(1,H,3) + mask + max-over-time.
// out[b,f,h] = max_{l: mask[b,l]!=0} ( sum_k x[b,l+k,f]*w[f,h,k] + bias[f,h] ), else -1e9.
//
// R6 structure: compacted WINDOW buffer in LDS (1 ds_read_b128 per valid l),
// l split across 2 lanes (4 waves/SIMD), packed v_pk_fma_f32/v_pk_max_f32.
// Probe R5 established: fixed harness overhead ~5.4us; R4 kernel device time
// was ~11.8us, LDS-pipe/latency bound (3.25 scalar ds_read per l, 2 waves/SIMD).

#define NEG_INF_F (-1e9f)

typedef float v2f __attribute__((ext_vector_type(2)));

constexpr int B_ = 128;
constexpr int V_ = 200;
constexpr int F_ = 64;
constexpr int H_ = 128;
constexpr int L_ = V_ - 3 + 1;   // 198

constexpr int NTHR = 256;
constexpr int FG   = 8;                    // features per block
constexpr int HPT  = 8;                    // h-outputs per thread (4 packed pairs)
constexpr int MAXW = (L_ + 7) & ~7;        // 200: max windows, padded to mult of 8
constexpr int WSTR = 4 * MAXW + 8;         // 808 floats: row stride (808%32=8 ->
                                           // f-rows 8 banks apart; 16B-aligned)

__global__ __launch_bounds__(NTHR)
void fve_kernel(const float* __restrict__ x,     // [B,V,F]
                const int*   __restrict__ mask,  // [B,1,L]
                const float* __restrict__ w,     // [F,H,K]
                const float* __restrict__ bias,  // [F,H]
                float* __restrict__ out)         // [B,F,H]
{
    __shared__ __align__(16) float xc[FG][WSTR];  // compacted windows: xc[f][4j+k]
    __shared__ int vlist[L_];
    __shared__ int vcnt;

    const int b  = blockIdx.x >> 3;        // grid = B * (F/FG) = 1024
    const int f0 = (blockIdx.x & 7) * FG;
    const int t  = threadIdx.x;

    if (t == 0) vcnt = 0;
    __syncthreads();

    // Phase A: compact valid time-steps (order irrelevant for max).
    if (t < L_ && mask[b * L_ + t] != 0) {
        const int p = atomicAdd(&vcnt, 1);
        vlist[p] = t;
    }
    __syncthreads();

    const int n    = vcnt;
    const int npad = (n + 7) & ~7;   // pad to mult of 8 (dup window 0; max is idempotent)

    // Phase B: build stride-4 windows straight from global:
    //   xc[fq*4+c][4j+k] = x[b, l_j+k, f0+fq*4+c],  k=0..2 (slot 3 = don't-care pad).
    // item = j*8 + k*2 + half ; k==3 lanes idle (25% of phase B only).
    for (int item = t; item < npad * 8; item += NTHR) {
        const int j    = item >> 3;
        const int k    = (item >> 1) & 3;
        const int half = item & 1;
        if (k == 3) continue;
        const int l = (j < n) ? vlist[j] : vlist[0];
        const float4 g = *reinterpret_cast<const float4*>(
            x + ((size_t)b * V_ + l + k) * F_ + f0 + half * 4);
        const int col = 4 * j + k;
        xc[half * 4 + 0][col] = g.x;
        xc[half * 4 + 1][col] = g.y;
        xc[half * 4 + 2][col] = g.z;
        xc[half * 4 + 3][col] = g.w;
    }
    __syncthreads();

    // Thread map: wave covers 2 f-rows; 16 h-lanes x 2 l-lanes per f.
    const int f_local = t >> 5;            // 0..7
    const int f       = f0 + f_local;
    const int h_lane  = (t >> 1) & 15;
    const int h0      = h_lane * HPT;      // 0,8,...,120
    const int l_lane  = t & 1;

    // Weights for h0..h0+7 repacked into h-pairs (layout in mem: [h][k]).
    const float* wp = w + ((size_t)f * H_ + h0) * 3;
    float wt[24];
#pragma unroll
    for (int j = 0; j < 6; ++j)
        *reinterpret_cast<float4*>(&wt[j * 4]) =
            *reinterpret_cast<const float4*>(wp + j * 4);

    float bsc[8];
    *reinterpret_cast<float4*>(&bsc[0]) =
        *reinterpret_cast<const float4*>(bias + (size_t)f * H_ + h0);
    *reinterpret_cast<float4*>(&bsc[4]) =
        *reinterpret_cast<const float4*>(bias + (size_t)f * H_ + h0 + 4);

    v2f wp0[4], wp1[4], wp2[4], bpk[4], mpk[4];
#pragma unroll
    for (int p = 0; p < 4; ++p) {
        wp0[p] = (v2f){wt[6 * p + 0], wt[6 * p + 3]};
        wp1[p] = (v2f){wt[6 * p + 1], wt[6 * p + 4]};
        wp2[p] = (v2f){wt[6 * p + 2], wt[6 * p + 5]};
        bpk[p] = (v2f){bsc[2 * p], bsc[2 * p + 1]};
        mpk[p] = (v2f){NEG_INF_F, NEG_INF_F};
    }

    const float4* xq = reinterpret_cast<const float4*>(&xc[f_local][0]);

#define PROCQ(Q)                                                              \
    do {                                                                      \
        const v2f X0 = (v2f){(Q).x, (Q).x};                                   \
        const v2f X1 = (v2f){(Q).y, (Q).y};                                   \
        const v2f X2 = (v2f){(Q).z, (Q).z};                                   \
        _Pragma("unroll")                                                     \
        for (int p = 0; p < 4; ++p) {                                         \
            const v2f c = __builtin_elementwise_fma(X0, wp0[p],               \
                          __builtin_elementwise_fma(X1, wp1[p],               \
                          __builtin_elementwise_fma(X2, wp2[p], bpk[p])));    \
            mpk[p] = __builtin_elementwise_max(mpk[p], c);                    \
        }                                                                     \
    } while (0)

    // Inner loop: 1 ds_read_b128 per window; lane handles windows l_lane, +2, +4...
    // npad % 8 == 0 -> per-lane trip count % 4 == 0: clean 4x unroll, loads batched.
    for (int u = 0; u < npad; u += 8) {
        const int i0 = u + l_lane;
        const float4 q0 = xq[i0];
        const float4 q1 = xq[i0 + 2];
        const float4 q2 = xq[i0 + 4];
        const float4 q3 = xq[i0 + 6];
        PROCQ(q0);
        PROCQ(q1);
        PROCQ(q2);
        PROCQ(q3);
    }
#undef PROCQ

    // Reduce across the l_lane pair (lanes t, t^1 hold same (f,h0)).
#pragma unroll
    for (int p = 0; p < 4; ++p) {
        const float a = __shfl_xor(mpk[p].x, 1, 64);
        const float c = __shfl_xor(mpk[p].y, 1, 64);
        mpk[p].x = fmaxf(mpk[p].x, a);
        mpk[p].y = fmaxf(mpk[p].y, c);
    }

    // Each lane writes one float4: l_lane 0 -> h0..h0+3, l_lane 1 -> h0+4..h0+7.
    float* op = out + ((size_t)b * F_ + f) * H_ + h0 + l_lane * 4;
    const int pb = l_lane * 2;
    *reinterpret_cast<float4*>(op) =
        make_float4(mpk[pb].x, mpk[pb].y, mpk[pb + 1].x, mpk[pb + 1].y);
}

extern "C" void kernel_launch(void* const* d_in, const int* in_sizes, int n_in,
                              void* d_out, int out_size, void* d_ws, size_t ws_size,
                              hipStream_t stream) {
    const float* x    = (const float*)d_in[0];  // input_visit
    const int*   mask = (const int*)d_in[1];    // visit_mask
    const float* w    = (const float*)d_in[2];  // conv_w
    const float* bias = (const float*)d_in[3];  // conv_b
    float* out = (float*)d_out;

    const int grid = B_ * (F_ / FG);  // 1024
    fve_kernel<<<grid, NTHR, 0, stream>>>(x, mask, w, bias, out);
}